// Round 10
// baseline (194.182 us; speedup 1.0000x reference)
//
#include <hip/hip_runtime.h>
#include <stdint.h>

typedef unsigned short u16;
typedef float f32x4 __attribute__((ext_vector_type(4)));
typedef __bf16 bf16x8 __attribute__((ext_vector_type(8)));
typedef short s16x4 __attribute__((ext_vector_type(4)));

__device__ __forceinline__ u16 f2bf(float f) {
  union { float f; uint32_t u; } c; c.f = f;
  uint32_t u = c.u;
  u += 0x7fffu + ((u >> 16) & 1u);   // RNE
  return (u16)(u >> 16);
}

// pack two fp32 into one dword of 2 bf16 (truncation)
__device__ __forceinline__ uint32_t pkbf(float a, float b) {
  union { float f; uint32_t u; } ua, ub; ua.f = a; ub.f = b;
  return __builtin_amdgcn_perm(ub.u, ua.u, 0x07060302u);
}

// global -> LDS direct copy, 16B per lane. LDS dest = wave-uniform base + lane*16.
#define GLOAD_LDS16(g, l)                                                              \
  __builtin_amdgcn_global_load_lds((__attribute__((address_space(1))) void*)(g),       \
                                   (__attribute__((address_space(3))) void*)(l), 16, 0, 0)

// ---------------------------------------------------------------- fused fp32->bf16
__global__ __launch_bounds__(256) void cvt_all(const float* __restrict__ x,
                                               const float* __restrict__ wq,
                                               const float* __restrict__ wk,
                                               const float* __restrict__ wv,
                                               const float* __restrict__ wo,
                                               u16* __restrict__ xb,
                                               u16* __restrict__ wqkvb,
                                               u16* __restrict__ wob) {
  int bx = blockIdx.x;
  const float* src;
  u16* dst;
  int i;
  if (bx < 4096) {
    src = x; dst = xb; i = bx * 256 + threadIdx.x;
  } else {
    int r = bx - 4096;
    int w = r >> 10;
    i = (r & 1023) * 256 + threadIdx.x;
    if (w == 0)      { src = wq; dst = wqkvb; }
    else if (w == 1) { src = wk; dst = wqkvb + 1048576; }
    else if (w == 2) { src = wv; dst = wqkvb + 2097152; }
    else             { src = wo; dst = wob; }
  }
  const float4 v = ((const float4*)src)[i];
  ushort4 o;
  o.x = f2bf(v.x); o.y = f2bf(v.y); o.z = f2bf(v.z); o.w = f2bf(v.w);
  ((ushort4*)dst)[i] = o;
}

// ---------------------------------------------------------------- QKV projection
// 256x256 TILE, 512 thr / 8 waves (2M x 4N), per-wave output 128x64: per BK=32
// step each wave does 32 MFMA (160cy) per 12 ds_read_b128 (144cy) -> MFMA-bound
// (the 128^2 tile's 16-MFMA/8-read = 80/96cy was ds_read-bound, the ~300 TF
// ceiling). Staging machinery UNCHANGED from the proven r2 kernel: XOR swizzle,
// rotating 3-buffer, stage 2 tiles ahead, counted vmcnt(4). LDS 96KB ->
// 1 block/CU, 2 waves/SIMD. Same K-tile order -> bitwise-identical results.
// Grid 12x16: blockIdx.x 0..3 -> Q (*0.125*log2e), 4..7 -> K, 8..11 -> Vt.
__global__ __launch_bounds__(512, 2) void gemm_qkv(const u16* __restrict__ A,
                                                   const u16* __restrict__ B,
                                                   u16* __restrict__ QKb,
                                                   u16* __restrict__ Vt) {
  const int K = 1024;
  __shared__ __align__(16) u16 sA[3 * 8192];   // 3 bufs x [256 rows][32] swizzled
  __shared__ __align__(16) u16 sB[3 * 8192];
  const int tid = threadIdx.x;        // 0..511
  const int lane = tid & 63;
  const int wave = tid >> 6;          // 0..7
  const int quad = lane >> 4, l16 = lane & 15;
  const int wr = (wave >> 2) * 128;   // wave row base: 0 or 128
  const int wc = (wave & 3) * 64;     // wave col base: 0,64,128,192
  const int bm = blockIdx.y * 256, bn = blockIdx.x * 256;

  f32x4 acc[8][4];
#pragma unroll
  for (int i = 0; i < 8; i++)
#pragma unroll
    for (int j = 0; j < 4; j++) acc[i][j] = (f32x4){0.f, 0.f, 0.f, 0.f};

  // stage one K-tile (A 16KB + B 16KB): 4 loads/thread. 16B unit u: row=u>>2,
  // stored unit (u&3) holds global col ((u&3)^(row&3))*8 — same swizzle as r2.
#define QKV_STAGE(t, bi)                                                           \
  {                                                                                \
    const int k0s = (t) * 32;                                                      \
    char* dA = (char*)(sA + (bi) * 8192);                                          \
    char* dB = (char*)(sB + (bi) * 8192);                                          \
    _Pragma("unroll")                                                              \
    for (int k2 = 0; k2 < 2; k2++) {                                               \
      int u = k2 * 512 + tid;                                                      \
      int row = u >> 2, c4 = (u & 3) ^ (row & 3);                                  \
      GLOAD_LDS16(A + (size_t)(bm + row) * K + k0s + c4 * 8, dA + u * 16);         \
      GLOAD_LDS16(B + (size_t)(bn + row) * K + k0s + c4 * 8, dB + u * 16);         \
    }                                                                              \
  }

  QKV_STAGE(0, 0);
  QKV_STAGE(1, 1);

  int cur = 0, stg = 2;
  for (int T = 0; T < 32; ++T) {
    // outstanding = {tile T (4), tile T+1 (4)}; vmcnt(4) lands tile T.
    if (T < 31) asm volatile("s_waitcnt vmcnt(4)" ::: "memory");
    else        asm volatile("s_waitcnt vmcnt(0)" ::: "memory");
    __builtin_amdgcn_s_barrier();
    asm volatile("" ::: "memory");
    if (T < 30) QKV_STAGE(T + 2, stg);   // buf(stg)'s old readers passed barrier

    const u16* cA = sA + cur * 8192;
    const u16* cB = sB + cur * 8192;
    bf16x8 af[8], bfr[4];
#pragma unroll
    for (int mt = 0; mt < 8; mt++) {
      int ra = wr + mt * 16 + l16;
      af[mt] = *(const bf16x8*)&cA[ra * 32 + ((quad ^ (ra & 3)) * 8)];
    }
#pragma unroll
    for (int nt = 0; nt < 4; nt++) {
      int rb = wc + nt * 16 + l16;
      bfr[nt] = *(const bf16x8*)&cB[rb * 32 + ((quad ^ (rb & 3)) * 8)];
    }
#pragma unroll
    for (int mt = 0; mt < 8; mt++)
#pragma unroll
      for (int nt = 0; nt < 4; nt++)
        acc[mt][nt] = __builtin_amdgcn_mfma_f32_16x16x32_bf16(af[mt], bfr[nt], acc[mt][nt], 0, 0, 0);

    cur = (cur == 2) ? 0 : cur + 1;
    stg = (stg == 2) ? 0 : stg + 1;
  }
#undef QKV_STAGE

  if (blockIdx.x < 8) {
    // Q gets 1/sqrt(d_k) * log2(e) folded in (softmax uses exp2)
    const float qs = (blockIdx.x < 4) ? 0.18033688011f : 1.0f;
#pragma unroll
    for (int mt = 0; mt < 8; mt++)
#pragma unroll
      for (int nt = 0; nt < 4; nt++)
#pragma unroll
        for (int r = 0; r < 4; r++) {
          int row = bm + wr + mt * 16 + quad * 4 + r;
          int col = bn + wc + nt * 16 + l16;
          QKb[(size_t)row * 2048 + col] = f2bf(acc[mt][nt][r] * qs);
        }
  } else {
#pragma unroll
    for (int mt = 0; mt < 8; mt++)
#pragma unroll
      for (int nt = 0; nt < 4; nt++) {
        int hd = (bn - 2048) + wc + nt * 16 + l16;
        int tok = bm + wr + mt * 16 + quad * 4;
        ushort4 o;
        o.x = f2bf(acc[mt][nt][0]);
        o.y = f2bf(acc[mt][nt][1]);
        o.z = f2bf(acc[mt][nt][2]);
        o.w = f2bf(acc[mt][nt][3]);
        *(ushort4*)&Vt[(size_t)hd * 4096 + tok] = o;
      }
  }
}

// ---------------------------------------------------------------- flash attention
// PIPELINED VERSION (T15, r8 — frozen at its ~48us plateau; structural knobs
// occupancy/dup/pipelining all measured null): at iter t, QK-MFMA tile t into
// regs; exp/pack/PV for tile t-1. V in 4-buffer rotation (72KB LDS), K 3-buf,
// counted vmcnt. 512 thr / 8 waves (4 q-groups x 2 kv-halves).
__global__ __launch_bounds__(512, 4) void attn_fwd(const u16* __restrict__ QKb,
                                                   const u16* __restrict__ Vt,
                                                   u16* __restrict__ O) {
  const int bx = blockIdx.x;
  const int qt = bx >> 5;         // 0..15 (BQ=128)
  const int h  = (bx >> 1) & 15;
  const int b  = bx & 1;
  const int tid = threadIdx.x;    // 0..511
  const int lane = tid & 63;
  const int wave = tid >> 6;      // 0..7
  const int wq = wave >> 1;       // q group: rows [wq*32, wq*32+32)
  const int wk = wave & 1;        // kv half: rows [wk*32, wk*32+32)
  const int quad = lane >> 4, l16 = lane & 15;

  // 72 KB: sQ[128x64] | sK 3x[64x64] | sV 4x[64x64]
  __shared__ __align__(16) u16 smem[36864];
  u16* sQ = smem;                 // [0, 16K)
  u16* sK = smem + 8192;          // [16K, 40K) 3 bufs
  u16* sV = smem + 20480;         // [40K, 72K) 4 bufs

  const int tok0 = b * 2048;
  const int q0 = qt * 128;
  const int colh = h * 64;

  // ---- prologue: Q (2 loads/thread), K/V tiles 0,1 (2 loads/thread each t)
#pragma unroll
  for (int k2 = 0; k2 < 2; k2++) {
    int c = k2 * 512 + tid;
    int row = c >> 3, c8 = (c & 7) ^ (row & 7);
    GLOAD_LDS16(QKb + (size_t)(tok0 + q0 + row) * 2048 + colh + c8 * 8,
                (char*)sQ + c * 16);
  }
#pragma unroll
  for (int t = 0; t < 2; t++) {
    int c = tid;
    int row = c >> 3, c8 = (c & 7) ^ (row & 7);
    GLOAD_LDS16(QKb + (size_t)(tok0 + t * 64 + row) * 2048 + 1024 + colh + c8 * 8,
                (char*)(sK + t * 4096) + c * 16);
    GLOAD_LDS16(Vt + (size_t)(colh + row) * 4096 + tok0 + t * 64 + c8 * 8,
                (char*)(sV + t * 4096) + c * 16);
  }
  // land Q (leave K0V0 + K1V1 = 4 loads in flight)
  asm volatile("s_waitcnt vmcnt(4)" ::: "memory");
  __builtin_amdgcn_s_barrier();
  asm volatile("" ::: "memory");

  // ---- hoist this q-group's 32 q rows as B-op fragments (2 subs of 16)
  bf16x8 aq[2][2];
#pragma unroll
  for (int sub = 0; sub < 2; sub++)
#pragma unroll
    for (int kh = 0; kh < 2; kh++) {
      int rq = wq * 32 + sub * 16 + l16;
      aq[sub][kh] = *(const bf16x8*)&sQ[rq * 64 + (((kh * 4 + quad) ^ (rq & 7)) * 8)];
    }

  f32x4 oacc[2][4];   // partial O^T over this wave's kv half: [q=sub*16+l16][d]
  float lsum[2];
#pragma unroll
  for (int sub = 0; sub < 2; sub++) {
    lsum[sub] = 0.f;
#pragma unroll
    for (int db = 0; db < 4; db++) oacc[sub][db] = (f32x4){0.f, 0.f, 0.f, 0.f};
  }

  int kc = 0, stg3 = 2;   // K-buffer rotation (3 bufs); V rotation is (tile&3)

#define ITER_LOAD(IT, SS)                                                            \
  {                                                                                  \
    asm volatile("s_waitcnt lgkmcnt(0)" ::: "memory");                               \
    if ((IT) < 31) asm volatile("s_waitcnt vmcnt(2)" ::: "memory");                  \
    else           asm volatile("s_waitcnt vmcnt(0)" ::: "memory");                  \
    __builtin_amdgcn_s_barrier();                                                    \
    asm volatile("" ::: "memory");                                                   \
    if ((IT) < 30) {                                                                 \
      const int nkv = ((IT) + 2) * 64;                                               \
      int c = tid;                                                                   \
      int row = c >> 3, c8 = (c & 7) ^ (row & 7);                                    \
      GLOAD_LDS16(QKb + (size_t)(tok0 + nkv + row) * 2048 + 1024 + colh + c8 * 8,    \
                  (char*)(sK + stg3 * 4096) + c * 16);                               \
      GLOAD_LDS16(Vt + (size_t)(colh + row) * 4096 + tok0 + nkv + c8 * 8,            \
                  (char*)(sV + (((IT) + 2) & 3) * 4096) + c * 16);                   \
    }                                                                                \
    const u16* sKc = sK + kc * 4096;                                                 \
    bf16x8 kf[2][2];                                                                 \
    _Pragma("unroll")                                                                \
    for (int nt = 0; nt < 2; nt++)                                                   \
      _Pragma("unroll")                                                              \
      for (int kh = 0; kh < 2; kh++) {                                               \
        int rr = wk * 32 + nt * 16 + l16;                                            \
        kf[nt][kh] = *(const bf16x8*)&sKc[rr * 64 + (((kh * 4 + quad) ^ (rr & 7)) * 8)]; \
      }                                                                              \
    _Pragma("unroll")                                                                \
    for (int sub = 0; sub < 2; sub++)                                                \
      _Pragma("unroll")                                                              \
      for (int nt = 0; nt < 2; nt++) {                                               \
        f32x4 c0 = (f32x4){0.f, 0.f, 0.f, 0.f};                                      \
        c0 = __builtin_amdgcn_mfma_f32_16x16x32_bf16(kf[nt][0], aq[sub][0], c0, 0, 0, 0); \
        SS[sub][nt] = __builtin_amdgcn_mfma_f32_16x16x32_bf16(kf[nt][1], aq[sub][1], c0, 0, 0, 0); \
      }                                                                              \
    kc = (kc == 2) ? 0 : kc + 1;                                                     \
    stg3 = (stg3 == 2) ? 0 : stg3 + 1;                                               \
  }

#define ITER_SOFT(TT, SS)                                                            \
  {                                                                                  \
    const u16* sVp = sV + ((TT) & 3) * 4096;                                         \
    _Pragma("unroll")                                                                \
    for (int nt = 0; nt < 2; nt++) {                                                 \
      s16x4 vf[4];                                                                   \
      _Pragma("unroll")                                                              \
      for (int db = 0; db < 4; db++) {                                               \
        int row = db * 16 + l16;                                                     \
        int c16 = ((wk * 2 + nt) * 2 + (quad >> 1)) ^ (row & 7);                     \
        vf[db] = *(const s16x4*)&sVp[row * 64 + c16 * 8 + (quad & 1) * 4];           \
      }                                                                              \
      _Pragma("unroll")                                                              \
      for (int sub = 0; sub < 2; sub++) {                                            \
        f32x4 cS = SS[sub][nt];                                                      \
        float e0 = __builtin_amdgcn_exp2f(cS[0]);                                    \
        float e1 = __builtin_amdgcn_exp2f(cS[1]);                                    \
        float e2 = __builtin_amdgcn_exp2f(cS[2]);                                    \
        float e3 = __builtin_amdgcn_exp2f(cS[3]);                                    \
        lsum[sub] += (e0 + e1) + (e2 + e3);                                          \
        union { uint32_t u[2]; s16x4 v; } bb;                                        \
        bb.u[0] = pkbf(e0, e1);                                                      \
        bb.u[1] = pkbf(e2, e3);                                                      \
        _Pragma("unroll")                                                            \
        for (int db = 0; db < 4; db++)                                               \
          oacc[sub][db] = __builtin_amdgcn_mfma_f32_16x16x16bf16_1k(vf[db], bb.v, oacc[sub][db], 0, 0, 0); \
      }                                                                              \
    }                                                                                \
  }

  f32x4 SA[2][2], SB[2][2];
  ITER_LOAD(0, SA);
  for (int it = 1; it < 31; it += 2) {
    ITER_LOAD(it, SB);
    ITER_SOFT(it - 1, SA);
    ITER_LOAD(it + 1, SA);
    ITER_SOFT(it, SB);
  }
  ITER_LOAD(31, SB);
  ITER_SOFT(30, SA);
  ITER_SOFT(31, SB);
#undef ITER_LOAD
#undef ITER_SOFT

  // ---- epilogue: pairwise cross-wave reduction (wk=0 writes, wk=1 combines)
  asm volatile("s_waitcnt lgkmcnt(0)" ::: "memory");
  __builtin_amdgcn_s_barrier();         // all loop LDS reads retired

#pragma unroll
  for (int sub = 0; sub < 2; sub++) {
    float v = lsum[sub];
    v += __shfl_xor(v, 16, 64);
    v += __shfl_xor(v, 32, 64);
    lsum[sub] = v;
  }

  // Rbase: 4 groups x [32 q][64 d] f32 (8 KB each) at bytes [0, 32K) — overlays
  // dead sQ + sK bufs 0,1. lsumT at [32K, 32K+512) — overlays dead sK buf2.
  float* Rbase = (float*)smem + wq * 2048;
  float* lsumT = (float*)((char*)smem + 32768);

  if (wk == 0) {
#pragma unroll
    for (int sub = 0; sub < 2; sub++) {
#pragma unroll
      for (int db = 0; db < 4; db++) {
        int q = sub * 16 + l16;
        int d = db * 16 + quad * 4;
        *(f32x4*)&Rbase[q * 64 + (d ^ ((q & 7) << 3))] = oacc[sub][db];
      }
      if (quad == 0) lsumT[wq * 32 + sub * 16 + l16] = lsum[sub];
    }
  }
  __builtin_amdgcn_s_barrier();
  if (wk == 1) {
#pragma unroll
    for (int sub = 0; sub < 2; sub++) {
      int q = sub * 16 + l16;
      float rt = 1.0f / (lsum[sub] + lsumT[wq * 32 + q]);
#pragma unroll
      for (int db = 0; db < 4; db++) {
        int d = db * 16 + quad * 4;
        f32x4 o = *(const f32x4*)&Rbase[q * 64 + (d ^ ((q & 7) << 3))] + oacc[sub][db];
        ushort4 st;
        st.x = f2bf(o[0] * rt);
        st.y = f2bf(o[1] * rt);
        st.z = f2bf(o[2] * rt);
        st.w = f2bf(o[3] * rt);
        *(ushort4*)&O[(size_t)(tok0 + q0 + wq * 32 + q) * 1024 + colh + d] = st;
      }
    }
  }
}

// ---------------------------------------------------------------- final projection
// REVERTED to r8: 128x64 tiles, BK=32, rotating 3-buffer + counted vmcnt
// (r9's BK=64 2-phase regressed ~5us — depth-1 prefetch + drain exposed latency).
__global__ __launch_bounds__(256) void gemm_out(const u16* __restrict__ A,
                                                const u16* __restrict__ B,
                                                float* __restrict__ C) {
  const int N = 1024, K = 1024;
  __shared__ __align__(16) u16 sA[3 * 4096];   // 3 x [128][32]
  __shared__ __align__(16) u16 sB[3 * 2048];   // 3 x [64][32]
  const int tid = threadIdx.x;
  const int lane = tid & 63;
  const int wave = tid >> 6;
  const int quad = lane >> 4, l16 = lane & 15;
  const int wm = (wave >> 1) * 64, wn = (wave & 1) * 32;
  const int bm = blockIdx.y * 128, bn = blockIdx.x * 64;

  f32x4 acc[4][2];
#pragma unroll
  for (int i = 0; i < 4; i++)
#pragma unroll
    for (int j = 0; j < 2; j++) acc[i][j] = (f32x4){0.f, 0.f, 0.f, 0.f};

#define OUT_STAGE(t, bi)                                                           \
  {                                                                                \
    const int k0s = (t) * 32;                                                      \
    char* dA = (char*)(sA + (bi) * 4096);                                          \
    char* dB = (char*)(sB + (bi) * 2048);                                          \
    _Pragma("unroll")                                                              \
    for (int k2 = 0; k2 < 2; k2++) {                                               \
      int u = k2 * 256 + tid;                                                      \
      int row = u >> 2, c4 = (u & 3) ^ (row & 3);                                  \
      GLOAD_LDS16(A + (size_t)(bm + row) * K + k0s + c4 * 8, dA + u * 16);         \
    }                                                                              \
    {                                                                              \
      int u = tid;                                                                 \
      int row = u >> 2, c4 = (u & 3) ^ (row & 3);                                  \
      GLOAD_LDS16(B + (size_t)(bn + row) * K + k0s + c4 * 8, dB + u * 16);         \
    }                                                                              \
  }

  OUT_STAGE(0, 0);
  OUT_STAGE(1, 1);

  int cur = 0, stg = 2;
  for (int T = 0; T < 32; ++T) {
    if (T < 31) asm volatile("s_waitcnt vmcnt(3)" ::: "memory");
    else        asm volatile("s_waitcnt vmcnt(0)" ::: "memory");
    __builtin_amdgcn_s_barrier();
    asm volatile("" ::: "memory");
    if (T < 30) OUT_STAGE(T + 2, stg);

    const u16* cA = sA + cur * 4096;
    const u16* cB = sB + cur * 2048;
    bf16x8 af[4], bfr[2];
#pragma unroll
    for (int mt = 0; mt < 4; mt++) {
      int ra = wm + mt * 16 + l16;
      af[mt] = *(const bf16x8*)&cA[ra * 32 + ((quad ^ (ra & 3)) * 8)];
    }
#pragma unroll
    for (int nt = 0; nt < 2; nt++) {
      int rb = wn + nt * 16 + l16;
      bfr[nt] = *(const bf16x8*)&cB[rb * 32 + ((quad ^ (rb & 3)) * 8)];
    }
#pragma unroll
    for (int mt = 0; mt < 4; mt++)
#pragma unroll
      for (int nt = 0; nt < 2; nt++)
        acc[mt][nt] = __builtin_amdgcn_mfma_f32_16x16x32_bf16(af[mt], bfr[nt], acc[mt][nt], 0, 0, 0);

    cur = (cur == 2) ? 0 : cur + 1;
    stg = (stg == 2) ? 0 : stg + 1;
  }
#undef OUT_STAGE

#pragma unroll
  for (int mt = 0; mt < 4; mt++)
#pragma unroll
    for (int nt = 0; nt < 2; nt++)
#pragma unroll
      for (int r = 0; r < 4; r++) {
        int row = bm + wm + mt * 16 + quad * 4 + r;
        int col = bn + wn + nt * 16 + l16;
        C[(size_t)row * N + col] = acc[mt][nt][r];
      }
}

// ---------------------------------------------------------------- launch
extern "C" void kernel_launch(void* const* d_in, const int* in_sizes, int n_in,
                              void* d_out, int out_size, void* d_ws, size_t ws_size,
                              hipStream_t stream) {
  const float* x  = (const float*)d_in[0];
  const float* wq = (const float*)d_in[1];
  const float* wk = (const float*)d_in[2];
  const float* wv = (const float*)d_in[3];
  const float* wo = (const float*)d_in[4];
  float* out = (float*)d_out;
  char* ws = (char*)d_ws;
  const size_t MB = 1u << 20;

  u16* xb    = (u16*)(ws);            // 8 MB  [4096 x 1024] bf16 x
  u16* wqkvb = (u16*)(ws + 8 * MB);   // 6 MB  [3072 x 1024]
  u16* wob   = (u16*)(ws + 14 * MB);  // 2 MB
  u16* QKb   = (u16*)(ws + 16 * MB);  // 16 MB [4096 x 2048] (Q*s | K)
  u16* Vtb   = (u16*)(ws + 32 * MB);  // 8 MB  [1024 hd x 4096 tok]
  u16* Ob    = xb;                    // alias: x dead after QKV gemm

  cvt_all<<<8192, 256, 0, stream>>>(x, wq, wk, wv, wo, xb, wqkvb, wob);

  gemm_qkv<<<dim3(12, 16), 512, 0, stream>>>(xb, wqkvb, QKb, Vtb);

  attn_fwd<<<512, 512, 0, stream>>>(QKb, Vtb, Ob);

  gemm_out<<<dim3(16, 32), 256, 0, stream>>>(Ob, wob, out);
}

// Round 11
// 176.251 us; speedup vs baseline: 1.1017x; 1.1017x over previous
//
#include <hip/hip_runtime.h>
#include <stdint.h>

typedef unsigned short u16;
typedef float f32x4 __attribute__((ext_vector_type(4)));
typedef __bf16 bf16x8 __attribute__((ext_vector_type(8)));
typedef short s16x4 __attribute__((ext_vector_type(4)));

__device__ __forceinline__ u16 f2bf(float f) {
  union { float f; uint32_t u; } c; c.f = f;
  uint32_t u = c.u;
  u += 0x7fffu + ((u >> 16) & 1u);   // RNE
  return (u16)(u >> 16);
}

// pack two fp32 into one dword of 2 bf16 (truncation)
__device__ __forceinline__ uint32_t pkbf(float a, float b) {
  union { float f; uint32_t u; } ua, ub; ua.f = a; ub.f = b;
  return __builtin_amdgcn_perm(ub.u, ua.u, 0x07060302u);
}

// global -> LDS direct copy, 16B per lane. LDS dest = wave-uniform base + lane*16.
#define GLOAD_LDS16(g, l)                                                              \
  __builtin_amdgcn_global_load_lds((__attribute__((address_space(1))) void*)(g),       \
                                   (__attribute__((address_space(3))) void*)(l), 16, 0, 0)

// ---------------------------------------------------------------- fused fp32->bf16
__global__ __launch_bounds__(256) void cvt_all(const float* __restrict__ x,
                                               const float* __restrict__ wq,
                                               const float* __restrict__ wk,
                                               const float* __restrict__ wv,
                                               const float* __restrict__ wo,
                                               u16* __restrict__ xb,
                                               u16* __restrict__ wqkvb,
                                               u16* __restrict__ wob) {
  int bx = blockIdx.x;
  const float* src;
  u16* dst;
  int i;
  if (bx < 4096) {
    src = x; dst = xb; i = bx * 256 + threadIdx.x;
  } else {
    int r = bx - 4096;
    int w = r >> 10;
    i = (r & 1023) * 256 + threadIdx.x;
    if (w == 0)      { src = wq; dst = wqkvb; }
    else if (w == 1) { src = wk; dst = wqkvb + 1048576; }
    else if (w == 2) { src = wv; dst = wqkvb + 2097152; }
    else             { src = wo; dst = wob; }
  }
  const float4 v = ((const float4*)src)[i];
  ushort4 o;
  o.x = f2bf(v.x); o.y = f2bf(v.y); o.z = f2bf(v.z); o.w = f2bf(v.w);
  ((ushort4*)dst)[i] = o;
}

// ---------------------------------------------------------------- QKV projection
// REVERTED to r2-exact (best measured total): 128x128 tile, BK=32, rotating
// 3-buffer, stage 2 tiles ahead, counted vmcnt(4). 768 blocks = 3 blocks/CU —
// the inter-block overlap is what masks the per-iter stalls (r10's 256^2 at
// 1 block/CU exposed them: MfmaUtil 17%).
// C cols 0..1023 -> Q * (0.125*log2e), 1024..2047 -> K; 2048..3071 -> Vt.
__global__ __launch_bounds__(256, 3) void gemm_qkv(const u16* __restrict__ A,
                                                   const u16* __restrict__ B,
                                                   u16* __restrict__ QKb,
                                                   u16* __restrict__ Vt) {
  const int K = 1024;
  __shared__ __align__(16) u16 sA[3 * 4096];   // 3 bufs x [128 rows][32] swizzled
  __shared__ __align__(16) u16 sB[3 * 4096];
  const int tid = threadIdx.x;
  const int lane = tid & 63;
  const int wave = tid >> 6;
  const int quad = lane >> 4, l16 = lane & 15;
  const int wm = (wave >> 1) * 64, wn = (wave & 1) * 64;
  const int bm = blockIdx.y * 128, bn = blockIdx.x * 128;

  f32x4 acc[4][4];
#pragma unroll
  for (int i = 0; i < 4; i++)
#pragma unroll
    for (int j = 0; j < 4; j++) acc[i][j] = (f32x4){0.f, 0.f, 0.f, 0.f};

#define QKV_STAGE(t, bi)                                                           \
  {                                                                                \
    const int k0s = (t) * 32;                                                      \
    char* dA = (char*)(sA + (bi) * 4096);                                          \
    char* dB = (char*)(sB + (bi) * 4096);                                          \
    _Pragma("unroll")                                                              \
    for (int k2 = 0; k2 < 2; k2++) {                                               \
      int u = k2 * 256 + tid;                                                      \
      int row = u >> 2, c4 = (u & 3) ^ (row & 3);                                  \
      GLOAD_LDS16(A + (size_t)(bm + row) * K + k0s + c4 * 8, dA + u * 16);         \
      GLOAD_LDS16(B + (size_t)(bn + row) * K + k0s + c4 * 8, dB + u * 16);         \
    }                                                                              \
  }

  QKV_STAGE(0, 0);
  QKV_STAGE(1, 1);

  int cur = 0, stg = 2;
  for (int T = 0; T < 32; ++T) {
    if (T < 31) asm volatile("s_waitcnt vmcnt(4)" ::: "memory");
    else        asm volatile("s_waitcnt vmcnt(0)" ::: "memory");
    __builtin_amdgcn_s_barrier();
    asm volatile("" ::: "memory");
    if (T < 30) QKV_STAGE(T + 2, stg);

    const u16* cA = sA + cur * 4096;
    const u16* cB = sB + cur * 4096;
    bf16x8 af[4], bfr[4];
#pragma unroll
    for (int mt = 0; mt < 4; mt++) {
      int ra = wm + mt * 16 + l16;
      af[mt] = *(const bf16x8*)&cA[ra * 32 + ((quad ^ (ra & 3)) * 8)];
    }
#pragma unroll
    for (int nt = 0; nt < 4; nt++) {
      int rb = wn + nt * 16 + l16;
      bfr[nt] = *(const bf16x8*)&cB[rb * 32 + ((quad ^ (rb & 3)) * 8)];
    }
#pragma unroll
    for (int mt = 0; mt < 4; mt++)
#pragma unroll
      for (int nt = 0; nt < 4; nt++)
        acc[mt][nt] = __builtin_amdgcn_mfma_f32_16x16x32_bf16(af[mt], bfr[nt], acc[mt][nt], 0, 0, 0);

    cur = (cur == 2) ? 0 : cur + 1;
    stg = (stg == 2) ? 0 : stg + 1;
  }
#undef QKV_STAGE

  if (blockIdx.x < 16) {
    const float qs = (blockIdx.x < 8) ? 0.18033688011f : 1.0f;
#pragma unroll
    for (int mt = 0; mt < 4; mt++)
#pragma unroll
      for (int nt = 0; nt < 4; nt++)
#pragma unroll
        for (int r = 0; r < 4; r++) {
          int row = bm + wm + mt * 16 + quad * 4 + r;
          int col = bn + wn + nt * 16 + l16;
          QKb[(size_t)row * 2048 + col] = f2bf(acc[mt][nt][r] * qs);
        }
  } else {
#pragma unroll
    for (int mt = 0; mt < 4; mt++)
#pragma unroll
      for (int nt = 0; nt < 4; nt++) {
        int hd = (bn - 2048) + wn + nt * 16 + l16;
        int tok = bm + wm + mt * 16 + quad * 4;
        ushort4 o;
        o.x = f2bf(acc[mt][nt][0]);
        o.y = f2bf(acc[mt][nt][1]);
        o.z = f2bf(acc[mt][nt][2]);
        o.w = f2bf(acc[mt][nt][3]);
        *(ushort4*)&Vt[(size_t)hd * 4096 + tok] = o;
      }
  }
}

// ---------------------------------------------------------------- flash attention
// PIPELINED VERSION (T15, r8 — frozen at its ~48us plateau): at iter t, QK-MFMA
// tile t into regs; exp/pack/PV for tile t-1. V in 4-buffer rotation (72KB LDS),
// K 3-buf, counted vmcnt. 512 thr / 8 waves (4 q-groups x 2 kv-halves).
__global__ __launch_bounds__(512, 4) void attn_fwd(const u16* __restrict__ QKb,
                                                   const u16* __restrict__ Vt,
                                                   u16* __restrict__ O) {
  const int bx = blockIdx.x;
  const int qt = bx >> 5;         // 0..15 (BQ=128)
  const int h  = (bx >> 1) & 15;
  const int b  = bx & 1;
  const int tid = threadIdx.x;    // 0..511
  const int lane = tid & 63;
  const int wave = tid >> 6;      // 0..7
  const int wq = wave >> 1;       // q group: rows [wq*32, wq*32+32)
  const int wk = wave & 1;        // kv half: rows [wk*32, wk*32+32)
  const int quad = lane >> 4, l16 = lane & 15;

  // 72 KB: sQ[128x64] | sK 3x[64x64] | sV 4x[64x64]
  __shared__ __align__(16) u16 smem[36864];
  u16* sQ = smem;                 // [0, 16K)
  u16* sK = smem + 8192;          // [16K, 40K) 3 bufs
  u16* sV = smem + 20480;         // [40K, 72K) 4 bufs

  const int tok0 = b * 2048;
  const int q0 = qt * 128;
  const int colh = h * 64;

  // ---- prologue: Q (2 loads/thread), K/V tiles 0,1 (2 loads/thread each t)
#pragma unroll
  for (int k2 = 0; k2 < 2; k2++) {
    int c = k2 * 512 + tid;
    int row = c >> 3, c8 = (c & 7) ^ (row & 7);
    GLOAD_LDS16(QKb + (size_t)(tok0 + q0 + row) * 2048 + colh + c8 * 8,
                (char*)sQ + c * 16);
  }
#pragma unroll
  for (int t = 0; t < 2; t++) {
    int c = tid;
    int row = c >> 3, c8 = (c & 7) ^ (row & 7);
    GLOAD_LDS16(QKb + (size_t)(tok0 + t * 64 + row) * 2048 + 1024 + colh + c8 * 8,
                (char*)(sK + t * 4096) + c * 16);
    GLOAD_LDS16(Vt + (size_t)(colh + row) * 4096 + tok0 + t * 64 + c8 * 8,
                (char*)(sV + t * 4096) + c * 16);
  }
  // land Q (leave K0V0 + K1V1 = 4 loads in flight)
  asm volatile("s_waitcnt vmcnt(4)" ::: "memory");
  __builtin_amdgcn_s_barrier();
  asm volatile("" ::: "memory");

  // ---- hoist this q-group's 32 q rows as B-op fragments (2 subs of 16)
  bf16x8 aq[2][2];
#pragma unroll
  for (int sub = 0; sub < 2; sub++)
#pragma unroll
    for (int kh = 0; kh < 2; kh++) {
      int rq = wq * 32 + sub * 16 + l16;
      aq[sub][kh] = *(const bf16x8*)&sQ[rq * 64 + (((kh * 4 + quad) ^ (rq & 7)) * 8)];
    }

  f32x4 oacc[2][4];   // partial O^T over this wave's kv half: [q=sub*16+l16][d]
  float lsum[2];
#pragma unroll
  for (int sub = 0; sub < 2; sub++) {
    lsum[sub] = 0.f;
#pragma unroll
    for (int db = 0; db < 4; db++) oacc[sub][db] = (f32x4){0.f, 0.f, 0.f, 0.f};
  }

  int kc = 0, stg3 = 2;   // K-buffer rotation (3 bufs); V rotation is (tile&3)

#define ITER_LOAD(IT, SS)                                                            \
  {                                                                                  \
    asm volatile("s_waitcnt lgkmcnt(0)" ::: "memory");                               \
    if ((IT) < 31) asm volatile("s_waitcnt vmcnt(2)" ::: "memory");                  \
    else           asm volatile("s_waitcnt vmcnt(0)" ::: "memory");                  \
    __builtin_amdgcn_s_barrier();                                                    \
    asm volatile("" ::: "memory");                                                   \
    if ((IT) < 30) {                                                                 \
      const int nkv = ((IT) + 2) * 64;                                               \
      int c = tid;                                                                   \
      int row = c >> 3, c8 = (c & 7) ^ (row & 7);                                    \
      GLOAD_LDS16(QKb + (size_t)(tok0 + nkv + row) * 2048 + 1024 + colh + c8 * 8,    \
                  (char*)(sK + stg3 * 4096) + c * 16);                               \
      GLOAD_LDS16(Vt + (size_t)(colh + row) * 4096 + tok0 + nkv + c8 * 8,            \
                  (char*)(sV + (((IT) + 2) & 3) * 4096) + c * 16);                   \
    }                                                                                \
    const u16* sKc = sK + kc * 4096;                                                 \
    bf16x8 kf[2][2];                                                                 \
    _Pragma("unroll")                                                                \
    for (int nt = 0; nt < 2; nt++)                                                   \
      _Pragma("unroll")                                                              \
      for (int kh = 0; kh < 2; kh++) {                                               \
        int rr = wk * 32 + nt * 16 + l16;                                            \
        kf[nt][kh] = *(const bf16x8*)&sKc[rr * 64 + (((kh * 4 + quad) ^ (rr & 7)) * 8)]; \
      }                                                                              \
    _Pragma("unroll")                                                                \
    for (int sub = 0; sub < 2; sub++)                                                \
      _Pragma("unroll")                                                              \
      for (int nt = 0; nt < 2; nt++) {                                               \
        f32x4 c0 = (f32x4){0.f, 0.f, 0.f, 0.f};                                      \
        c0 = __builtin_amdgcn_mfma_f32_16x16x32_bf16(kf[nt][0], aq[sub][0], c0, 0, 0, 0); \
        SS[sub][nt] = __builtin_amdgcn_mfma_f32_16x16x32_bf16(kf[nt][1], aq[sub][1], c0, 0, 0, 0); \
      }                                                                              \
    kc = (kc == 2) ? 0 : kc + 1;                                                     \
    stg3 = (stg3 == 2) ? 0 : stg3 + 1;                                               \
  }

#define ITER_SOFT(TT, SS)                                                            \
  {                                                                                  \
    const u16* sVp = sV + ((TT) & 3) * 4096;                                         \
    _Pragma("unroll")                                                                \
    for (int nt = 0; nt < 2; nt++) {                                                 \
      s16x4 vf[4];                                                                   \
      _Pragma("unroll")                                                              \
      for (int db = 0; db < 4; db++) {                                               \
        int row = db * 16 + l16;                                                     \
        int c16 = ((wk * 2 + nt) * 2 + (quad >> 1)) ^ (row & 7);                     \
        vf[db] = *(const s16x4*)&sVp[row * 64 + c16 * 8 + (quad & 1) * 4];           \
      }                                                                              \
      _Pragma("unroll")                                                              \
      for (int sub = 0; sub < 2; sub++) {                                            \
        f32x4 cS = SS[sub][nt];                                                      \
        float e0 = __builtin_amdgcn_exp2f(cS[0]);                                    \
        float e1 = __builtin_amdgcn_exp2f(cS[1]);                                    \
        float e2 = __builtin_amdgcn_exp2f(cS[2]);                                    \
        float e3 = __builtin_amdgcn_exp2f(cS[3]);                                    \
        lsum[sub] += (e0 + e1) + (e2 + e3);                                          \
        union { uint32_t u[2]; s16x4 v; } bb;                                        \
        bb.u[0] = pkbf(e0, e1);                                                      \
        bb.u[1] = pkbf(e2, e3);                                                      \
        _Pragma("unroll")                                                            \
        for (int db = 0; db < 4; db++)                                               \
          oacc[sub][db] = __builtin_amdgcn_mfma_f32_16x16x16bf16_1k(vf[db], bb.v, oacc[sub][db], 0, 0, 0); \
      }                                                                              \
    }                                                                                \
  }

  f32x4 SA[2][2], SB[2][2];
  ITER_LOAD(0, SA);
  for (int it = 1; it < 31; it += 2) {
    ITER_LOAD(it, SB);
    ITER_SOFT(it - 1, SA);
    ITER_LOAD(it + 1, SA);
    ITER_SOFT(it, SB);
  }
  ITER_LOAD(31, SB);
  ITER_SOFT(30, SA);
  ITER_SOFT(31, SB);
#undef ITER_LOAD
#undef ITER_SOFT

  // ---- epilogue: pairwise cross-wave reduction (wk=0 writes, wk=1 combines)
  asm volatile("s_waitcnt lgkmcnt(0)" ::: "memory");
  __builtin_amdgcn_s_barrier();         // all loop LDS reads retired

#pragma unroll
  for (int sub = 0; sub < 2; sub++) {
    float v = lsum[sub];
    v += __shfl_xor(v, 16, 64);
    v += __shfl_xor(v, 32, 64);
    lsum[sub] = v;
  }

  // Rbase: 4 groups x [32 q][64 d] f32 (8 KB each) at bytes [0, 32K) — overlays
  // dead sQ + sK bufs 0,1. lsumT at [32K, 32K+512) — overlays dead sK buf2.
  float* Rbase = (float*)smem + wq * 2048;
  float* lsumT = (float*)((char*)smem + 32768);

  if (wk == 0) {
#pragma unroll
    for (int sub = 0; sub < 2; sub++) {
#pragma unroll
      for (int db = 0; db < 4; db++) {
        int q = sub * 16 + l16;
        int d = db * 16 + quad * 4;
        *(f32x4*)&Rbase[q * 64 + (d ^ ((q & 7) << 3))] = oacc[sub][db];
      }
      if (quad == 0) lsumT[wq * 32 + sub * 16 + l16] = lsum[sub];
    }
  }
  __builtin_amdgcn_s_barrier();
  if (wk == 1) {
#pragma unroll
    for (int sub = 0; sub < 2; sub++) {
      int q = sub * 16 + l16;
      float rt = 1.0f / (lsum[sub] + lsumT[wq * 32 + q]);
#pragma unroll
      for (int db = 0; db < 4; db++) {
        int d = db * 16 + quad * 4;
        f32x4 o = *(const f32x4*)&Rbase[q * 64 + (d ^ ((q & 7) << 3))] + oacc[sub][db];
        ushort4 st;
        st.x = f2bf(o[0] * rt);
        st.y = f2bf(o[1] * rt);
        st.z = f2bf(o[2] * rt);
        st.w = f2bf(o[3] * rt);
        *(ushort4*)&O[(size_t)(tok0 + q0 + wq * 32 + q) * 1024 + colh + d] = st;
      }
    }
  }
}

// ---------------------------------------------------------------- final projection
// 128x64 tiles at 512 blocks (2/CU), BK=64, rotating 3-BUFFER counted vmcnt(6)
// — r9's BK=64 failure was the 2-buffer drain, not BK; this keeps the proven
// depth-2 counted ledger and halves the barrier count (16 iters vs 32).
// FP association per 32-chunk unchanged (kh=0 then kh=1 sequential).
__global__ __launch_bounds__(256, 2) void gemm_out(const u16* __restrict__ A,
                                                   const u16* __restrict__ B,
                                                   float* __restrict__ C) {
  const int N = 1024, K = 1024;
  __shared__ __align__(16) u16 sA[3 * 8192];   // 3 x [128][64] swizzled
  __shared__ __align__(16) u16 sB[3 * 4096];   // 3 x [64][64]
  const int tid = threadIdx.x;
  const int lane = tid & 63;
  const int wave = tid >> 6;
  const int quad = lane >> 4, l16 = lane & 15;
  const int wm = (wave >> 1) * 64, wn = (wave & 1) * 32;
  const int bm = blockIdx.y * 128, bn = blockIdx.x * 64;

  f32x4 acc[4][2];
#pragma unroll
  for (int i = 0; i < 4; i++)
#pragma unroll
    for (int j = 0; j < 2; j++) acc[i][j] = (f32x4){0.f, 0.f, 0.f, 0.f};

  // stage one K-tile: A [128][64] = 4 loads/thread, B [64][64] = 2 loads/thread.
  // 16B unit u: row=u>>3, chunk (u&7) holds global chunk ((u&7)^(row&7)).
#define OUT_STAGE(t, bi)                                                           \
  {                                                                                \
    const int k0s = (t) * 64;                                                      \
    char* dA = (char*)(sA + (bi) * 8192);                                          \
    char* dB = (char*)(sB + (bi) * 4096);                                          \
    _Pragma("unroll")                                                              \
    for (int k2 = 0; k2 < 4; k2++) {                                               \
      int u = k2 * 256 + tid;                                                      \
      int row = u >> 3, c8 = (u & 7) ^ (row & 7);                                  \
      GLOAD_LDS16(A + (size_t)(bm + row) * K + k0s + c8 * 8, dA + u * 16);         \
    }                                                                              \
    _Pragma("unroll")                                                              \
    for (int k2 = 0; k2 < 2; k2++) {                                               \
      int u = k2 * 256 + tid;                                                      \
      int row = u >> 3, c8 = (u & 7) ^ (row & 7);                                  \
      GLOAD_LDS16(B + (size_t)(bn + row) * K + k0s + c8 * 8, dB + u * 16);         \
    }                                                                              \
  }

  OUT_STAGE(0, 0);
  OUT_STAGE(1, 1);

  int cur = 0, stg = 2;
  for (int T = 0; T < 16; ++T) {
    // outstanding = {tile T (6), tile T+1 (6)}; vmcnt(6) lands tile T.
    if (T < 15) asm volatile("s_waitcnt vmcnt(6)" ::: "memory");
    else        asm volatile("s_waitcnt vmcnt(0)" ::: "memory");
    __builtin_amdgcn_s_barrier();
    asm volatile("" ::: "memory");
    if (T < 14) OUT_STAGE(T + 2, stg);

    const u16* cA = sA + cur * 8192;
    const u16* cB = sB + cur * 4096;
    bf16x8 af[4][2], bfr[2][2];
#pragma unroll
    for (int mt = 0; mt < 4; mt++)
#pragma unroll
      for (int kh = 0; kh < 2; kh++) {
        int ra = wm + mt * 16 + l16;
        af[mt][kh] = *(const bf16x8*)&cA[ra * 64 + (((kh * 4 + quad) ^ (ra & 7)) * 8)];
      }
#pragma unroll
    for (int nt = 0; nt < 2; nt++)
#pragma unroll
      for (int kh = 0; kh < 2; kh++) {
        int rb = wn + nt * 16 + l16;
        bfr[nt][kh] = *(const bf16x8*)&cB[rb * 64 + (((kh * 4 + quad) ^ (rb & 7)) * 8)];
      }
#pragma unroll
    for (int mt = 0; mt < 4; mt++)
#pragma unroll
      for (int nt = 0; nt < 2; nt++) {
        acc[mt][nt] = __builtin_amdgcn_mfma_f32_16x16x32_bf16(af[mt][0], bfr[nt][0], acc[mt][nt], 0, 0, 0);
        acc[mt][nt] = __builtin_amdgcn_mfma_f32_16x16x32_bf16(af[mt][1], bfr[nt][1], acc[mt][nt], 0, 0, 0);
      }
    cur = (cur == 2) ? 0 : cur + 1;
    stg = (stg == 2) ? 0 : stg + 1;
  }
#undef OUT_STAGE

#pragma unroll
  for (int mt = 0; mt < 4; mt++)
#pragma unroll
    for (int nt = 0; nt < 2; nt++)
#pragma unroll
      for (int r = 0; r < 4; r++) {
        int row = bm + wm + mt * 16 + quad * 4 + r;
        int col = bn + wn + nt * 16 + l16;
        C[(size_t)row * N + col] = acc[mt][nt][r];
      }
}

// ---------------------------------------------------------------- launch
extern "C" void kernel_launch(void* const* d_in, const int* in_sizes, int n_in,
                              void* d_out, int out_size, void* d_ws, size_t ws_size,
                              hipStream_t stream) {
  const float* x  = (const float*)d_in[0];
  const float* wq = (const float*)d_in[1];
  const float* wk = (const float*)d_in[2];
  const float* wv = (const float*)d_in[3];
  const float* wo = (const float*)d_in[4];
  float* out = (float*)d_out;
  char* ws = (char*)d_ws;
  const size_t MB = 1u << 20;

  u16* xb    = (u16*)(ws);            // 8 MB  [4096 x 1024] bf16 x
  u16* wqkvb = (u16*)(ws + 8 * MB);   // 6 MB  [3072 x 1024]
  u16* wob   = (u16*)(ws + 14 * MB);  // 2 MB
  u16* QKb   = (u16*)(ws + 16 * MB);  // 16 MB [4096 x 2048] (Q*s | K)
  u16* Vtb   = (u16*)(ws + 32 * MB);  // 8 MB  [1024 hd x 4096 tok]
  u16* Ob    = xb;                    // alias: x dead after QKV gemm

  cvt_all<<<8192, 256, 0, stream>>>(x, wq, wk, wv, wo, xb, wqkvb, wob);

  gemm_qkv<<<dim3(24, 32), 256, 0, stream>>>(xb, wqkvb, QKb, Vtb);

  attn_fwd<<<512, 512, 0, stream>>>(QKb, Vtb, Ob);

  gemm_out<<<dim3(16, 32), 256, 0, stream>>>(Ob, wob, out);
}